// Round 2
// baseline (72.180 us; speedup 1.0000x reference)
//
#include <hip/hip_runtime.h>

// ---------------------------------------------------------------------------
// LIIF forward, MI355X.
//   k_prepw     : repack weights to fragment-major f16 streams in ws
//   k_transpose : x [B,C,H,W] f32 -> xt [B,H,W,C] f16
//   k_stage1    : P[b,pix,128] = unfold3x3(x) @ w0[0:576] + b0   (16x16x32 MFMA)
//   k_stage2    : barrier-free in-register MLP: 32x32x16 MFMA, D->B via
//                 cvt_pk + v_permlane32_swap_b32; corners combined by shfl.
// B=2, C=64, H=W=128, Q=8192.
// ---------------------------------------------------------------------------

typedef unsigned short U16;
typedef unsigned int   u32;
using f16x8  = __attribute__((ext_vector_type(8)))  _Float16;
using f32x4  = __attribute__((ext_vector_type(4)))  float;
using f32x16 = __attribute__((ext_vector_type(16))) float;
using u16x8  = __attribute__((ext_vector_type(8)))  U16;
using u16x4  = __attribute__((ext_vector_type(4)))  U16;

// ws layout (f16 element offsets)
#define XT_OFF   0          // 2*128*128*64 = 2,097,152
#define P_OFF    2097152    // 2*16384*128  = 4,194,304
#define W0F_OFF  6291456    // 73,728  stage1 A-frags: [kpos][ks][mtile][lane][8]
#define W1F_OFF  6365184    // 3*16384 stage2 A-frags: [s][mt][lane][8]
#define W4F_OFF  6414336    // 8,192   stage2 final:   [s][mt4][lane][8]

__device__ __forceinline__ float h2f(U16 u){ _Float16 h; __builtin_memcpy(&h,&u,2); return (float)h; }
__device__ __forceinline__ U16 f2h(float f){ _Float16 h = (_Float16)f; U16 u; __builtin_memcpy(&u,&h,2); return u; }
__device__ __forceinline__ u32 packf16(float a, float b){
  _Float16 ha = (_Float16)a, hb = (_Float16)b;
  U16 ua, ub; __builtin_memcpy(&ua,&ha,2); __builtin_memcpy(&ub,&hb,2);
  return (u32)ua | ((u32)ub << 16);
}
__device__ __forceinline__ f16x8 bfrag(const u32* w){
  union { u32 u[4]; f16x8 v; } t;
  t.u[0]=w[0]; t.u[1]=w[1]; t.u[2]=w[2]; t.u[3]=w[3];
  return t.v;
}

__device__ __forceinline__ int nearest_idx(float g){
  float t = (g + 1.0f) * 128.0f;   // exact
  t = (t - 1.0f) * 0.5f;           // exact
  float r = rintf(t);              // half-even == np.round
  r = fminf(fmaxf(r, 0.0f), 127.0f);
  return (int)r;
}
__device__ __forceinline__ float seqv(int i){ return -0.9921875f + 0.015625f*(float)i; }

// corner: 0:(-1,-1) 1:(-1,+1) 2:(+1,-1) 3:(+1,+1)
__device__ __forceinline__ void corner_calc(float c0, float c1, int corner,
                                            int& iy, int& ix, float& rel0, float& rel1){
  const float rx = 0.0078125f;
  float sx = (corner & 2) ? rx : -rx;
  float sy = (corner & 1) ? rx : -rx;
  float a0 = c0 + sx; a0 = a0 + 1e-6f; a0 = fminf(fmaxf(a0, -1.0f + 1e-6f), 1.0f - 1e-6f);
  float a1 = c1 + sy; a1 = a1 + 1e-6f; a1 = fminf(fmaxf(a1, -1.0f + 1e-6f), 1.0f - 1e-6f);
  iy = nearest_idx(a0);
  ix = nearest_idx(a1);
  rel0 = (c0 - seqv(ix)) * 128.0f;   // ref quirk: rel0 uses seq[ix]
  rel1 = (c1 - seqv(iy)) * 128.0f;
}

// ---------------------------------------------------------------------------
__global__ __launch_bounds__(256) void k_prepw(const float* __restrict__ w0,
    const float* __restrict__ w1, const float* __restrict__ w2,
    const float* __restrict__ w3, const float* __restrict__ w4,
    U16* __restrict__ ws)
{
  int i = blockIdx.x * 256 + threadIdx.x;   // 512 blocks -> 131072 elems
  float v; int dst;
  if (i < 73728) {
    // w0f[kpos][ks][mtile][lane][e] = w0[(c*9+kpos)*128 + o]
    int e = i & 7, lane = (i >> 3) & 63, mtile = (i >> 9) & 7, ks = (i >> 12) & 1, kpos = i >> 13;
    int o = (mtile << 4) + (lane & 15);
    int c = (ks << 5) + ((lane >> 4) << 3) + e;
    v = w0[(c * 9 + kpos) * 128 + o];
    dst = W0F_OFF + i;
  } else if (i < 122880) {
    // wLf[s][mt][lane][e] = wL[k*128 + m]
    int j = i - 73728; int L = j >> 14; int loc = j & 16383;
    int e = loc & 7, lane = (loc >> 3) & 63, mt = (loc >> 9) & 3, s = loc >> 11;
    int m = (mt << 5) + (lane & 31);
    int k = (s << 4) + ((lane >> 5) << 3) + e;
    const float* src = (L == 0) ? w1 : (L == 1) ? w2 : w3;
    v = src[(k << 7) + m];
    dst = W1F_OFF + j;
  } else {
    // w4f[s][mt4][lane][e] = w4[k*64 + m]
    int j = i - 122880;
    int e = j & 7, lane = (j >> 3) & 63, mt4 = (j >> 9) & 1, s = j >> 10;
    int m = (mt4 << 5) + (lane & 31);
    int k = (s << 4) + ((lane >> 5) << 3) + e;
    v = w4[(k << 6) + m];
    dst = W4F_OFF + j;
  }
  ws[dst] = f2h(v);
}

// ---------------------------------------------------------------------------
// x [B,C,H,W] f32 -> xt [B,H,W,C] f16.
__global__ __launch_bounds__(256) void k_transpose(const float* __restrict__ x,
                                                   U16* __restrict__ xt)
{
  __shared__ U16 t[64 * 72];
  const int tid = threadIdx.x, bid = blockIdx.x;
  const int xh = bid & 1, y = (bid >> 1) & 127, b = bid >> 8;
  const int x0 = xh << 6;
  {
    int cc = tid & 63, seg = tid >> 6;
    const float* src = x + (((size_t)((b << 6) + cc)) << 14) + (y << 7) + x0 + (seg << 4);
    U16 h[16];
    #pragma unroll
    for (int e = 0; e < 16; e += 4) {
      float4 v = *(const float4*)(src + e);
      h[e] = f2h(v.x); h[e+1] = f2h(v.y); h[e+2] = f2h(v.z); h[e+3] = f2h(v.w);
    }
    int sw = (cc & 7) << 3;
    u16x8 lo, hi;
    #pragma unroll
    for (int e = 0; e < 8; ++e) { lo[e] = h[e]; hi[e] = h[e+8]; }
    *(u16x8*)(&t[cc*72 + (((seg << 4)    ) ^ sw)]) = lo;
    *(u16x8*)(&t[cc*72 + (((seg << 4) + 8) ^ sw)]) = hi;
  }
  __syncthreads();
  {
    int xx = tid & 63, seg = tid >> 6;
    U16 h[16];
    #pragma unroll
    for (int j = 0; j < 16; ++j) {
      int c = (seg << 4) + j;
      h[j] = t[c*72 + (xx ^ ((c & 7) << 3))];
    }
    U16* dst = xt + ((size_t)(((b << 7) + y) << 7) + x0 + xx) * 64 + (seg << 4);
    u16x8 lo, hi;
    #pragma unroll
    for (int e = 0; e < 8; ++e) { lo[e] = h[e]; hi[e] = h[e+8]; }
    *(u16x8*)(dst) = lo;
    *(u16x8*)(dst + 8) = hi;
  }
}

// ---------------------------------------------------------------------------
// Stage 1: conv3x3-as-GEMM, M=128 outch x N=128 pixels, K=9*64.
__global__ __launch_bounds__(256) void k_stage1(const U16* __restrict__ xt,
                                                const U16* __restrict__ w0f,
                                                const float* __restrict__ b0,
                                                U16* __restrict__ P)
{
  __shared__ U16 araw[3 * 130 * 64];
  const int tid = threadIdx.x;
  const int bid = blockIdx.x;
  const int b = bid >> 7, y = bid & 127;

  const u16x8 zero8 = {0,0,0,0,0,0,0,0};
  for (int dy = 0; dy < 3; ++dy) {
    int yy = y + dy - 1;
    #pragma unroll
    for (int it = 0; it < 4; ++it) {
      int u = tid + it * 256;
      int xp = 1 + (u >> 3);
      int c0 = (u & 7) << 3;
      u16x8 v = zero8;
      if (yy >= 0 && yy < 128) {
        int csrc = c0 ^ ((xp & 7) << 3);
        v = *(const u16x8*)(xt + ((size_t)(((b << 7) + yy) << 7) + (xp - 1)) * 64 + csrc);
      }
      *(u16x8*)(&araw[(dy * 130 + xp) * 64 + c0]) = v;
    }
  }
  if (tid < 48) {
    int dy = tid >> 4, which = (tid >> 3) & 1, c0 = (tid & 7) << 3;
    int xp = which ? 129 : 0;
    *(u16x8*)(&araw[(dy * 130 + xp) * 64 + c0]) = zero8;
  }
  __syncthreads();

  const int wv = tid >> 6, ln = tid & 63;
  const int lrow = ln & 15, lg = ln >> 4;

  f32x4 acc[2][8];
  #pragma unroll
  for (int m = 0; m < 2; ++m)
    #pragma unroll
    for (int n = 0; n < 8; ++n) acc[m][n] = (f32x4){0.f, 0.f, 0.f, 0.f};

  for (int kpos = 0; kpos < 9; ++kpos) {
    const int dyr = kpos / 3;
    const int dx = kpos % 3 - 1;
    f16x8 a[2][2];
    #pragma unroll
    for (int mf = 0; mf < 2; ++mf)
      #pragma unroll
      for (int ks = 0; ks < 2; ++ks) {
        size_t off = (((size_t)(kpos * 2 + ks) * 8 + (wv * 2 + mf)) * 64 + ln) * 8;
        a[mf][ks] = *(const f16x8*)(w0f + off);
      }
    #pragma unroll
    for (int ks = 0; ks < 2; ++ks)
      #pragma unroll
      for (int nf = 0; nf < 8; ++nf) {
        int xp = (nf << 4) + lrow + dx + 1;
        int cc = ((ks << 5) + (lg << 3)) ^ ((xp & 7) << 3);
        f16x8 bf = *(const f16x8*)(&araw[(dyr * 130 + xp) * 64 + cc]);
        acc[0][nf] = __builtin_amdgcn_mfma_f32_16x16x32_f16(a[0][ks], bf, acc[0][nf], 0, 0, 0);
        acc[1][nf] = __builtin_amdgcn_mfma_f32_16x16x32_f16(a[1][ks], bf, acc[1][nf], 0, 0, 0);
      }
  }

  #pragma unroll
  for (int mf = 0; mf < 2; ++mf) {
    int o0 = (wv << 5) + (mf << 4) + (lg << 2);
    float bb[4];
    #pragma unroll
    for (int r = 0; r < 4; ++r) bb[r] = b0[o0 + r];
    #pragma unroll
    for (int nf = 0; nf < 8; ++nf) {
      int pix = (nf << 4) + lrow;
      u16x4 w;
      #pragma unroll
      for (int r = 0; r < 4; ++r) w[r] = f2h(acc[mf][nf][r] + bb[r]);
      *(u16x4*)(P + ((size_t)((b << 14) + (y << 7) + pix)) * 128 + o0) = w;
    }
  }
}

// ---------------------------------------------------------------------------
// Stage 2: fully in-register MLP. Wave = 16 queries x 4 corners = 64 rows.
//   rows: nt in {0,1}, col = lane&31; corner = (col>>4)+2*nt, qi = col&15.
//   B-frag (32x32x16): n=col, k = 16s + 8*(lane>>5) + e
//   D: n=col, m = (r&3) + 8*(r>>2) + 4*(lane>>5)
//   D->nextB: p[j]=pack(d[2j],d[2j+1]); permlane32_swap(p[w+4u], p[w+4u+2])
//             -> B[s=2mt'+u] words {w, w+2}.
__global__ __launch_bounds__(256, 1) void k_stage2(
    const U16* __restrict__ P,
    const float* __restrict__ coord, const float* __restrict__ cell,
    const float* __restrict__ w0,
    const U16* __restrict__ w1f, const U16* __restrict__ w2f,
    const U16* __restrict__ w3f, const U16* __restrict__ w4f,
    const float* __restrict__ b1, const float* __restrict__ b2,
    const float* __restrict__ b3, const float* __restrict__ b4,
    float* __restrict__ out)
{
  const int tid = threadIdx.x;
  const int wv = tid >> 6, ln = tid & 63;
  const int wave = blockIdx.x * 4 + wv;
  const int q0 = wave << 4;
  const int col = ln & 31, h = ln >> 5;
  const int qi = col & 15;
  const int gq = q0 + qi;
  const int bimg = gq >> 13;

  float c0v = coord[gq * 2 + 0], c1v = coord[gq * 2 + 1];
  float rc0 = cell[gq * 2 + 0] * 128.0f, rc1 = cell[gq * 2 + 1] * 128.0f;

  int lin4[4]; float r0v[4], r1v[4], area[4];
  #pragma unroll
  for (int c = 0; c < 4; ++c) {
    int iy, ix; float r0, r1;
    corner_calc(c0v, c1v, c, iy, ix, r0, r1);
    lin4[c] = iy * 128 + ix;
    r0v[c] = r0; r1v[c] = r1;
    area[c] = fabsf(r0 * r1) + 1e-9f;
  }
  float tot = ((area[0] + area[1]) + area[2]) + area[3];
  const int cA = col >> 4;        // corner for nt=0
  const int cB = cA + 2;          // corner for nt=1
  float wgtA = area[3 - cA] / tot;
  float wgtB = area[3 - cB] / tot;

  // ---- build layer-1 B frags (h0) ----
  u32 Bf[2][8][4];
  {
    const U16* PrA = P + (((size_t)(bimg << 14) + lin4[cA]) << 7);
    const U16* PrB = P + (((size_t)(bimg << 14) + lin4[cB]) << 7);
    const float* tu = w0 + 576 * 128;
    const float* tv = w0 + 577 * 128;
    const float* ts = w0 + 578 * 128;
    const float* tt = w0 + 579 * 128;
    float rel0A = r0v[cA], rel1A = r1v[cA];
    float rel0B = r0v[cB], rel1B = r1v[cB];
    #pragma unroll
    for (int s = 0; s < 8; ++s) {
      int k0 = (s << 4) + (h << 3);
      f32x4 ua = *(const f32x4*)(tu + k0), ub = *(const f32x4*)(tu + k0 + 4);
      f32x4 va = *(const f32x4*)(tv + k0), vb = *(const f32x4*)(tv + k0 + 4);
      f32x4 sa = *(const f32x4*)(ts + k0), sb = *(const f32x4*)(ts + k0 + 4);
      f32x4 ta = *(const f32x4*)(tt + k0), tb = *(const f32x4*)(tt + k0 + 4);
      u16x8 pA = *(const u16x8*)(PrA + k0);
      u16x8 pB = *(const u16x8*)(PrB + k0);
      float hA[8], hB[8];
      #pragma unroll
      for (int e = 0; e < 8; ++e) {
        float uu = (e < 4) ? ua[e & 3] : ub[e & 3];
        float vv = (e < 4) ? va[e & 3] : vb[e & 3];
        float ss = (e < 4) ? sa[e & 3] : sb[e & 3];
        float t2 = (e < 4) ? ta[e & 3] : tb[e & 3];
        float base = rc0 * ss + rc1 * t2;
        hA[e] = fmaxf(h2f(pA[e]) + rel0A * uu + rel1A * vv + base, 0.0f);
        hB[e] = fmaxf(h2f(pB[e]) + rel0B * uu + rel1B * vv + base, 0.0f);
      }
      #pragma unroll
      for (int w = 0; w < 4; ++w) {
        Bf[0][s][w] = packf16(hA[2 * w], hA[2 * w + 1]);
        Bf[1][s][w] = packf16(hB[2 * w], hB[2 * w + 1]);
      }
    }
  }

  // ---- hidden layers 1..3 ----
  const U16* wf_[3] = {w1f, w2f, w3f};
  const float* bb_[3] = {b1, b2, b3};
  f32x16 acc[4][2];
  #pragma unroll
  for (int L = 0; L < 3; ++L) {
    const U16* wf = wf_[L];
    const float* bL = bb_[L];
    #pragma unroll
    for (int mt = 0; mt < 4; ++mt)
      #pragma unroll
      for (int j = 0; j < 4; ++j) {
        f32x4 bv = *(const f32x4*)(bL + (mt << 5) + (j << 3) + (h << 2));
        #pragma unroll
        for (int q = 0; q < 4; ++q) {
          acc[mt][0][4 * j + q] = bv[q];
          acc[mt][1][4 * j + q] = bv[q];
        }
      }
    #pragma unroll
    for (int s = 0; s < 8; ++s) {
      f16x8 B0 = bfrag(Bf[0][s]);
      f16x8 B1 = bfrag(Bf[1][s]);
      #pragma unroll
      for (int mt = 0; mt < 4; ++mt) {
        f16x8 A = *(const f16x8*)(wf + (((size_t)(s * 4 + mt) * 64 + ln) << 3));
        acc[mt][0] = __builtin_amdgcn_mfma_f32_32x32x16_f16(A, B0, acc[mt][0], 0, 0, 0);
        acc[mt][1] = __builtin_amdgcn_mfma_f32_32x32x16_f16(A, B1, acc[mt][1], 0, 0, 0);
      }
    }
    // D -> next-layer B (relu + pack + permlane32_swap)
    #pragma unroll
    for (int nt = 0; nt < 2; ++nt)
      #pragma unroll
      for (int mtp = 0; mtp < 4; ++mtp) {
        u32 p[8];
        #pragma unroll
        for (int j2 = 0; j2 < 8; ++j2)
          p[j2] = packf16(fmaxf(acc[mtp][nt][2 * j2], 0.0f),
                          fmaxf(acc[mtp][nt][2 * j2 + 1], 0.0f));
        #pragma unroll
        for (int u = 0; u < 2; ++u)
          #pragma unroll
          for (int w = 0; w < 2; ++w) {
            u32 va = p[w + 4 * u], vb = p[w + 4 * u + 2];
            asm("v_permlane32_swap_b32 %0, %1" : "+v"(va), "+v"(vb));
            Bf[nt][2 * mtp + u][w]     = va;
            Bf[nt][2 * mtp + u][w + 2] = vb;
          }
      }
  }

  // ---- final layer 128 -> 64 ----
  f32x16 a4[2][2];
  #pragma unroll
  for (int mt4 = 0; mt4 < 2; ++mt4)
    #pragma unroll
    for (int nt = 0; nt < 2; ++nt)
      #pragma unroll
      for (int r = 0; r < 16; ++r) a4[mt4][nt][r] = 0.0f;
  #pragma unroll
  for (int s = 0; s < 8; ++s) {
    f16x8 B0 = bfrag(Bf[0][s]);
    f16x8 B1 = bfrag(Bf[1][s]);
    #pragma unroll
    for (int mt4 = 0; mt4 < 2; ++mt4) {
      f16x8 A = *(const f16x8*)(w4f + (((size_t)(s * 2 + mt4) * 64 + ln) << 3));
      a4[mt4][0] = __builtin_amdgcn_mfma_f32_32x32x16_f16(A, B0, a4[mt4][0], 0, 0, 0);
      a4[mt4][1] = __builtin_amdgcn_mfma_f32_32x32x16_f16(A, B1, a4[mt4][1], 0, 0, 0);
    }
  }

  // ---- epilogue: area-weighted corner combine ----
  float tacc[2][16];
  #pragma unroll
  for (int mt4 = 0; mt4 < 2; ++mt4)
    #pragma unroll
    for (int r = 0; r < 16; ++r)
      tacc[mt4][r] = a4[mt4][0][r] * wgtA + a4[mt4][1][r] * wgtB;
  #pragma unroll
  for (int mt4 = 0; mt4 < 2; ++mt4)
    #pragma unroll
    for (int r = 0; r < 16; ++r)
      tacc[mt4][r] += __shfl_xor(tacc[mt4][r], 16, 64);

  if (!(ln & 16)) {
    #pragma unroll
    for (int mt4 = 0; mt4 < 2; ++mt4)
      #pragma unroll
      for (int j = 0; j < 4; ++j) {
        int mo = (mt4 << 5) + (j << 3) + (h << 2);
        f32x4 bv = *(const f32x4*)(b4 + mo);
        f32x4 res;
        #pragma unroll
        for (int q = 0; q < 4; ++q) res[q] = tacc[mt4][4 * j + q] + bv[q];
        *(f32x4*)(out + (size_t)gq * 64 + mo) = res;
      }
  }
}

// ---------------------------------------------------------------------------
extern "C" void kernel_launch(void* const* d_in, const int* in_sizes, int n_in,
                              void* d_out, int out_size, void* d_ws, size_t ws_size,
                              hipStream_t stream)
{
  const float* x     = (const float*)d_in[0];
  const float* coord = (const float*)d_in[1];
  const float* cell  = (const float*)d_in[2];
  const float* w0    = (const float*)d_in[3];
  const float* b0    = (const float*)d_in[4];
  const float* w1    = (const float*)d_in[5];
  const float* b1    = (const float*)d_in[6];
  const float* w2    = (const float*)d_in[7];
  const float* b2    = (const float*)d_in[8];
  const float* w3    = (const float*)d_in[9];
  const float* b3    = (const float*)d_in[10];
  const float* w4    = (const float*)d_in[11];
  const float* b4    = (const float*)d_in[12];
  U16* ws = (U16*)d_ws;

  hipLaunchKernelGGL(k_prepw,     dim3(512), dim3(256), 0, stream, w0, w1, w2, w3, w4, ws);
  hipLaunchKernelGGL(k_transpose, dim3(512), dim3(256), 0, stream, x, ws + XT_OFF);
  hipLaunchKernelGGL(k_stage1,    dim3(256), dim3(256), 0, stream,
                     ws + XT_OFF, ws + W0F_OFF, b0, ws + P_OFF);
  hipLaunchKernelGGL(k_stage2,    dim3(256), dim3(256), 0, stream,
                     ws + P_OFF, coord, cell, w0,
                     ws + W1F_OFF, ws + W1F_OFF + 16384, ws + W1F_OFF + 32768, ws + W4F_OFF,
                     b1, b2, b3, b4, (float*)d_out);
}

// Round 4
// 45.526 us; speedup vs baseline: 1.5855x; 1.5855x over previous
//
#include <hip/hip_runtime.h>

// ---------------------------------------------------------------------------
// LIIF forward, MI355X.
//   k_prep   : [blocks 0-511] x NCHW f32 -> NHWC f16; [512-561] weight repack
//              to MFMA-fragment-major f16 streams (coalesced via LDS transpose)
//   k_stage1 : P[b,pix,128] = unfold3x3(x) @ w0[0:576] + b0  (16x16x32 MFMA)
//   k_stage2 : in-register MLP, wave = 8 queries x 4 corners = 32 cols.
//              Weights direct from global (L1/L2-broadcast). 32x32x16 MFMA,
//              D->B via pack + v_permlane32_swap_b32. Corner combine by
//              4-lane shfl_xor. 512 blocks -> 2048 waves (2/SIMD).
// B=2, C=64, H=W=128, Q=8192 (16384 total query rows).
// ---------------------------------------------------------------------------

typedef unsigned short U16;
typedef unsigned int   u32;
using f16x8  = __attribute__((ext_vector_type(8)))  _Float16;
using f32x4  = __attribute__((ext_vector_type(4)))  float;
using f32x16 = __attribute__((ext_vector_type(16))) float;
using u16x8  = __attribute__((ext_vector_type(8)))  U16;
using u16x4  = __attribute__((ext_vector_type(4)))  U16;

// ws layout (f16 element offsets)
#define XT_OFF   0          // 2*128*128*64 = 2,097,152
#define P_OFF    2097152    // 2*16384*128  = 4,194,304
#define W0F_OFF  6291456    // 73,728  stage1 A-frags: [kpos][ks][mtile][lane][8]
#define W1F_OFF  6365184    // 3*16384 stage2 A-frags: [L][s][mt][lane][8]
#define W4F_OFF  6414336    // 8,192   stage2 final:   [s][mt4][lane][8]

__device__ __forceinline__ float h2f(U16 u){ _Float16 h; __builtin_memcpy(&h,&u,2); return (float)h; }
__device__ __forceinline__ U16 f2h(float f){ _Float16 h = (_Float16)f; U16 u; __builtin_memcpy(&u,&h,2); return u; }
__device__ __forceinline__ u32 packf16(float a, float b){
  _Float16 ha = (_Float16)a, hb = (_Float16)b;
  U16 ua, ub; __builtin_memcpy(&ua,&ha,2); __builtin_memcpy(&ub,&hb,2);
  return (u32)ua | ((u32)ub << 16);
}
__device__ __forceinline__ f16x8 bfrag(const u32* w){
  union { u32 u[4]; f16x8 v; } t;
  t.u[0]=w[0]; t.u[1]=w[1]; t.u[2]=w[2]; t.u[3]=w[3];
  return t.v;
}

__device__ __forceinline__ int nearest_idx(float g){
  float t = (g + 1.0f) * 128.0f;   // exact
  t = (t - 1.0f) * 0.5f;           // exact
  float r = rintf(t);              // half-even == np.round
  r = fminf(fmaxf(r, 0.0f), 127.0f);
  return (int)r;
}
__device__ __forceinline__ float seqv(int i){ return -0.9921875f + 0.015625f*(float)i; }

// corner: 0:(-1,-1) 1:(-1,+1) 2:(+1,-1) 3:(+1,+1)
__device__ __forceinline__ void corner_calc(float c0, float c1, int corner,
                                            int& iy, int& ix, float& rel0, float& rel1){
  const float rx = 0.0078125f;
  float sx = (corner & 2) ? rx : -rx;
  float sy = (corner & 1) ? rx : -rx;
  float a0 = c0 + sx; a0 = a0 + 1e-6f; a0 = fminf(fmaxf(a0, -1.0f + 1e-6f), 1.0f - 1e-6f);
  float a1 = c1 + sy; a1 = a1 + 1e-6f; a1 = fminf(fmaxf(a1, -1.0f + 1e-6f), 1.0f - 1e-6f);
  iy = nearest_idx(a0);
  ix = nearest_idx(a1);
  rel0 = (c0 - seqv(ix)) * 128.0f;   // ref quirk: rel0 uses seq[ix]
  rel1 = (c1 - seqv(iy)) * 128.0f;
}

// ---------------------------------------------------------------------------
// k_prep: 562 blocks.
//   [0,512)   : transpose x -> xt (f16 NHWC)
//   [512,536) : wL (w1/w2/w3) frag repack, block = (L, s)
//   [536,544) : w4 frag repack, block = s
//   [544,562) : w0 conv-weight frag repack, block = (kpos, ks)
__global__ __launch_bounds__(256) void k_prep(const float* __restrict__ x,
    const float* __restrict__ w0, const float* __restrict__ w1,
    const float* __restrict__ w2, const float* __restrict__ w3,
    const float* __restrict__ w4, U16* __restrict__ ws)
{
  __shared__ U16 sh[64 * 72];
  const int tid = threadIdx.x, bid = blockIdx.x;

  if (bid < 512) {
    // ---- transpose: x [B,C,H,W] f32 -> xt [B,H,W,C] f16 ----
    U16* xt = ws + XT_OFF;
    const int xh = bid & 1, y = (bid >> 1) & 127, b = bid >> 8;
    const int x0 = xh << 6;
    {
      int cc = tid & 63, seg = tid >> 6;
      const float* src = x + (((size_t)((b << 6) + cc)) << 14) + (y << 7) + x0 + (seg << 4);
      U16 hv[16];
      #pragma unroll
      for (int e = 0; e < 16; e += 4) {
        float4 v = *(const float4*)(src + e);
        hv[e] = f2h(v.x); hv[e+1] = f2h(v.y); hv[e+2] = f2h(v.z); hv[e+3] = f2h(v.w);
      }
      int sw = (cc & 7) << 3;
      u16x8 lo, hi;
      #pragma unroll
      for (int e = 0; e < 8; ++e) { lo[e] = hv[e]; hi[e] = hv[e+8]; }
      *(u16x8*)(&sh[cc*72 + (((seg << 4)    ) ^ sw)]) = lo;
      *(u16x8*)(&sh[cc*72 + (((seg << 4) + 8) ^ sw)]) = hi;
    }
    __syncthreads();
    {
      int xx = tid & 63, seg = tid >> 6;
      U16 hv[16];
      #pragma unroll
      for (int j = 0; j < 16; ++j) {
        int c = (seg << 4) + j;
        hv[j] = sh[c*72 + (xx ^ ((c & 7) << 3))];
      }
      U16* dst = xt + ((size_t)(((b << 7) + y) << 7) + x0 + xx) * 64 + (seg << 4);
      u16x8 lo, hi;
      #pragma unroll
      for (int e = 0; e < 8; ++e) { lo[e] = hv[e]; hi[e] = hv[e+8]; }
      *(u16x8*)(dst) = lo;
      *(u16x8*)(dst + 8) = hi;
    }
  } else if (bid < 536) {
    // ---- wL repack: wLf[s][mt][lane][e] = wL[k*128+m],
    //      m=(mt<<5)+(lane&31), k=(s<<4)+((lane>>5)<<3)+e ----
    int bid2 = bid - 512, L = bid2 >> 3, s = bid2 & 7;
    const float* src = (L == 0) ? w1 : (L == 1) ? w2 : w3;
    {
      int kk = tid >> 4, m0 = (tid & 15) << 3;
      const float* p = src + (((s << 4) + kk) << 7) + m0;
      float4 a = *(const float4*)p, b2v = *(const float4*)(p + 4);
      U16* d = &sh[kk * 128 + m0];
      d[0]=f2h(a.x); d[1]=f2h(a.y); d[2]=f2h(a.z); d[3]=f2h(a.w);
      d[4]=f2h(b2v.x); d[5]=f2h(b2v.y); d[6]=f2h(b2v.z); d[7]=f2h(b2v.w);
    }
    __syncthreads();
    {
      int mt = tid >> 6, lane = tid & 63;
      u16x8 o;
      #pragma unroll
      for (int e = 0; e < 8; ++e)
        o[e] = sh[((((lane >> 5) << 3) + e) << 7) + (mt << 5) + (lane & 31)];
      *(u16x8*)(ws + W1F_OFF + (L << 14) + (((s << 2) + mt) << 9) + (lane << 3)) = o;
    }
  } else if (bid < 544) {
    // ---- w4 repack: w4f[s][mt4][lane][e] = w4[k*64+m] ----
    int s = bid - 536;
    {
      int kk = tid >> 4, m0 = (tid & 15) << 2;
      float4 a = *(const float4*)(w4 + (((s << 4) + kk) << 6) + m0);
      U16* d = &sh[kk * 64 + m0];
      d[0]=f2h(a.x); d[1]=f2h(a.y); d[2]=f2h(a.z); d[3]=f2h(a.w);
    }
    __syncthreads();
    if (tid < 128) {
      int mt4 = tid >> 6, lane = tid & 63;
      u16x8 o;
      #pragma unroll
      for (int e = 0; e < 8; ++e)
        o[e] = sh[((((lane >> 5) << 3) + e) << 6) + (mt4 << 5) + (lane & 31)];
      *(u16x8*)(ws + W4F_OFF + (((s << 1) + mt4) << 9) + (lane << 3)) = o;
    }
  } else {
    // ---- w0f repack: w0f[kpos][ks][mtile][lane][e] = w0[(c*9+kpos)*128+o],
    //      o=(mtile<<4)+(lane&15), c=(ks<<5)+((lane>>4)<<3)+e ----
    int t2 = bid - 544, kpos = t2 >> 1, ks = t2 & 1;
    {
      int cc = tid >> 3, o0 = (tid & 7) << 4;
      const float* p = w0 + ((size_t)((((ks << 5) + cc) * 9) + kpos) << 7) + o0;
      #pragma unroll
      for (int j = 0; j < 4; ++j) {
        float4 v = *(const float4*)(p + (j << 2));
        U16* d = &sh[(cc << 7) + o0 + (j << 2)];
        d[0]=f2h(v.x); d[1]=f2h(v.y); d[2]=f2h(v.z); d[3]=f2h(v.w);
      }
    }
    __syncthreads();
    {
      int lane = tid & 63, mt0 = tid >> 6;
      #pragma unroll
      for (int i = 0; i < 2; ++i) {
        int mtile = mt0 + (i << 2);
        u16x8 o;
        #pragma unroll
        for (int e = 0; e < 8; ++e)
          o[e] = sh[((((lane >> 4) << 3) + e) << 7) + (mtile << 4) + (lane & 15)];
        *(u16x8*)(ws + W0F_OFF + (((((kpos << 1) + ks) << 3) + mtile) << 9) + (lane << 3)) = o;
      }
    }
  }
}

// ---------------------------------------------------------------------------
// Stage 1: conv3x3-as-GEMM. 512 blocks: (b, y, half-row of 64 px).
// M=128 outch x N=64 px, K=9*64. B in XOR-swizzled LDS, A from w0f (contig).
__global__ __launch_bounds__(256) void k_stage1(const U16* __restrict__ xt,
                                                const U16* __restrict__ w0f,
                                                const float* __restrict__ b0,
                                                U16* __restrict__ P)
{
  __shared__ U16 araw[3 * 66 * 64];   // [dy][xp][c^((xp&7)<<3)], xp local 0..65
  const int tid = threadIdx.x, bid = blockIdx.x;
  const int b = bid >> 8, rem = bid & 255;
  const int y = rem >> 1, x0 = (rem & 1) << 6;

  const u16x8 zero8 = {0,0,0,0,0,0,0,0};
  for (int dy = 0; dy < 3; ++dy) {
    int yy = y + dy - 1;
    for (int u = tid; u < 528; u += 256) {
      int xp = u >> 3, c0 = (u & 7) << 3;
      int xs = x0 + xp - 1;
      u16x8 v = zero8;
      if (yy >= 0 && yy < 128 && xs >= 0 && xs < 128) {
        int csrc = c0 ^ ((xp & 7) << 3);
        v = *(const u16x8*)(xt + ((size_t)(((b << 7) + yy) << 7) + xs) * 64 + csrc);
      }
      *(u16x8*)(&araw[(dy * 66 + xp) * 64 + c0]) = v;
    }
  }
  __syncthreads();

  const int wv = tid >> 6, ln = tid & 63;
  const int lrow = ln & 15, lg = ln >> 4;

  f32x4 acc[2][4];
  #pragma unroll
  for (int m = 0; m < 2; ++m)
    #pragma unroll
    for (int n = 0; n < 4; ++n) acc[m][n] = (f32x4){0.f, 0.f, 0.f, 0.f};

  #pragma unroll
  for (int kpos = 0; kpos < 9; ++kpos) {
    const int dyr = kpos / 3;
    const int dx = kpos % 3 - 1;
    f16x8 a[2][2];
    #pragma unroll
    for (int mf = 0; mf < 2; ++mf)
      #pragma unroll
      for (int ks = 0; ks < 2; ++ks) {
        size_t off = ((size_t)((((kpos << 1) + ks) << 3) + ((wv << 1) + mf)) << 9) + (ln << 3);
        a[mf][ks] = *(const f16x8*)(w0f + off);
      }
    #pragma unroll
    for (int ks = 0; ks < 2; ++ks)
      #pragma unroll
      for (int nf = 0; nf < 4; ++nf) {
        int xp = (nf << 4) + lrow + dx + 1;
        int cc = ((ks << 5) + (lg << 3)) ^ ((xp & 7) << 3);
        f16x8 bf = *(const f16x8*)(&araw[(dyr * 66 + xp) * 64 + cc]);
        acc[0][nf] = __builtin_amdgcn_mfma_f32_16x16x32_f16(a[0][ks], bf, acc[0][nf], 0, 0, 0);
        acc[1][nf] = __builtin_amdgcn_mfma_f32_16x16x32_f16(a[1][ks], bf, acc[1][nf], 0, 0, 0);
      }
  }

  #pragma unroll
  for (int mf = 0; mf < 2; ++mf) {
    int o0 = (wv << 5) + (mf << 4) + (lg << 2);
    float bb[4];
    #pragma unroll
    for (int r = 0; r < 4; ++r) bb[r] = b0[o0 + r];
    #pragma unroll
    for (int nf = 0; nf < 4; ++nf) {
      int px = x0 + (nf << 4) + lrow;
      u16x4 w;
      #pragma unroll
      for (int r = 0; r < 4; ++r) w[r] = f2h(acc[mf][nf][r] + bb[r]);
      *(u16x4*)(P + ((size_t)((b << 14) + (y << 7) + px)) * 128 + o0) = w;
    }
  }
}

// ---------------------------------------------------------------------------
// Stage 2: wave = 8 queries x 4 corners. col=lane&31: qi=col>>2, c=col&3.
// Weights read directly from global frag streams (as in the verified round-2
// kernel). B-frag (32x32x16): n=col, k=16s+8h+e.  D: n=col, m=(r&3)+8(r>>2)+4h.
// D->nextB: p[j]=pack(d2j,d2j+1); permlane32_swap(p[w+4u],p[w+4u+2]).
__global__ __launch_bounds__(256) void k_stage2(
    const U16* __restrict__ P,
    const float* __restrict__ coord, const float* __restrict__ cell,
    const float* __restrict__ w0,
    const U16* __restrict__ w1f, const U16* __restrict__ w2f,
    const U16* __restrict__ w3f, const U16* __restrict__ w4f,
    const float* __restrict__ b1, const float* __restrict__ b2,
    const float* __restrict__ b3, const float* __restrict__ b4,
    float* __restrict__ out)
{
  const int tid = threadIdx.x;
  const int wv = tid >> 6, ln = tid & 63;
  const int wave = blockIdx.x * 4 + wv;
  const int q0 = wave << 3;
  const int col = ln & 31, h = ln >> 5;
  const int qi = col >> 2, c = col & 3;
  const int gq = q0 + qi;
  const int bimg = gq >> 13;

  // ---- per-query corner math ----
  float c0v = coord[gq * 2 + 0], c1v = coord[gq * 2 + 1];
  float rc0 = cell[gq * 2 + 0] * 128.0f, rc1 = cell[gq * 2 + 1] * 128.0f;
  int lin4[4]; float r0v[4], r1v[4], area[4];
  #pragma unroll
  for (int c4 = 0; c4 < 4; ++c4) {
    int iy, ix; float r0, r1;
    corner_calc(c0v, c1v, c4, iy, ix, r0, r1);
    lin4[c4] = iy * 128 + ix;
    r0v[c4] = r0; r1v[c4] = r1;
    area[c4] = fabsf(r0 * r1) + 1e-9f;
  }
  float tot = ((area[0] + area[1]) + area[2]) + area[3];
  float wgt = area[3 - c] / tot;           // perm = (3,2,1,0)
  float rel0 = r0v[c], rel1 = r1v[c];

  // ---- P row prefetch (8 independent 16B loads) ----
  const U16* Pr = P + ((size_t)(bimg << 14) + lin4[c]) * 128;
  u16x8 pv[8];
  #pragma unroll
  for (int s = 0; s < 8; ++s)
    pv[s] = *(const u16x8*)(Pr + (s << 4) + (h << 3));

  // ---- h0 -> Bf ----
  u32 Bf[8][4];
  {
    const float* tu = w0 + 576 * 128;
    const float* tv = tu + 128;
    const float* ts2 = tv + 128;
    const float* tt = ts2 + 128;
    #pragma unroll
    for (int s = 0; s < 8; ++s) {
      int k0 = (s << 4) + (h << 3);
      f32x4 ua = *(const f32x4*)(tu + k0),  ub = *(const f32x4*)(tu + k0 + 4);
      f32x4 va = *(const f32x4*)(tv + k0),  vb = *(const f32x4*)(tv + k0 + 4);
      f32x4 sa = *(const f32x4*)(ts2 + k0), sb = *(const f32x4*)(ts2 + k0 + 4);
      f32x4 ta = *(const f32x4*)(tt + k0),  tb = *(const f32x4*)(tt + k0 + 4);
      float hh[8];
      #pragma unroll
      for (int e = 0; e < 8; ++e) {
        float uu = (e < 4) ? ua[e & 3] : ub[e & 3];
        float vvv = (e < 4) ? va[e & 3] : vb[e & 3];
        float ss = (e < 4) ? sa[e & 3] : sb[e & 3];
        float t2 = (e < 4) ? ta[e & 3] : tb[e & 3];
        hh[e] = fmaxf(h2f(pv[s][e]) + rel0 * uu + rel1 * vvv + rc0 * ss + rc1 * t2, 0.0f);
      }
      #pragma unroll
      for (int w = 0; w < 4; ++w)
        Bf[s][w] = packf16(hh[2 * w], hh[2 * w + 1]);
    }
  }

  // ---- hidden layers 1..3 (weights direct from global) ----
  const U16* wf_[3] = {w1f, w2f, w3f};
  const float* bL_[3] = {b1, b2, b3};
  #pragma unroll
  for (int L = 0; L < 3; ++L) {
    const U16* wf = wf_[L];
    const float* bL = bL_[L];
    f32x16 acc[4];
    #pragma unroll
    for (int mt = 0; mt < 4; ++mt)
      #pragma unroll
      for (int j = 0; j < 4; ++j) {
        f32x4 bv = *(const f32x4*)(bL + (mt << 5) + (j << 3) + (h << 2));
        #pragma unroll
        for (int q = 0; q < 4; ++q) acc[mt][4 * j + q] = bv[q];
      }
    #pragma unroll
    for (int s = 0; s < 8; ++s) {
      f16x8 B = bfrag(Bf[s]);
      #pragma unroll
      for (int mt = 0; mt < 4; ++mt) {
        f16x8 A = *(const f16x8*)(wf + (((size_t)(s * 4 + mt) * 64 + ln) << 3));
        acc[mt] = __builtin_amdgcn_mfma_f32_32x32x16_f16(A, B, acc[mt], 0, 0, 0);
      }
    }
    // D -> next-layer B
    #pragma unroll
    for (int mtp = 0; mtp < 4; ++mtp) {
      u32 p[8];
      #pragma unroll
      for (int j2 = 0; j2 < 8; ++j2)
        p[j2] = packf16(fmaxf(acc[mtp][2 * j2], 0.0f), fmaxf(acc[mtp][2 * j2 + 1], 0.0f));
      #pragma unroll
      for (int u = 0; u < 2; ++u)
        #pragma unroll
        for (int w = 0; w < 2; ++w) {
          u32 va = p[w + 4 * u], vb = p[w + 4 * u + 2];
          asm("v_permlane32_swap_b32 %0, %1" : "+v"(va), "+v"(vb));
          Bf[2 * mtp + u][w]     = va;
          Bf[2 * mtp + u][w + 2] = vb;
        }
    }
  }

  // ---- final layer 128 -> 64 ----
  f32x16 a4[2];
  #pragma unroll
  for (int mt4 = 0; mt4 < 2; ++mt4)
    #pragma unroll
    for (int r = 0; r < 16; ++r) a4[mt4][r] = 0.0f;
  #pragma unroll
  for (int s = 0; s < 8; ++s) {
    f16x8 B = bfrag(Bf[s]);
    #pragma unroll
    for (int mt4 = 0; mt4 < 2; ++mt4) {
      f16x8 A = *(const f16x8*)(w4f + (((size_t)(s * 2 + mt4) * 64 + ln) << 3));
      a4[mt4] = __builtin_amdgcn_mfma_f32_32x32x16_f16(A, B, a4[mt4], 0, 0, 0);
    }
  }

  // ---- area-weighted corner combine across 4-lane groups ----
  float tacc[2][16];
  #pragma unroll
  for (int mt4 = 0; mt4 < 2; ++mt4)
    #pragma unroll
    for (int r = 0; r < 16; ++r) {
      float v = a4[mt4][r] * wgt;
      v += __shfl_xor(v, 1, 64);
      v += __shfl_xor(v, 2, 64);
      tacc[mt4][r] = v;
    }

  if (c == 0) {
    #pragma unroll
    for (int mt4 = 0; mt4 < 2; ++mt4)
      #pragma unroll
      for (int j = 0; j < 4; ++j) {
        int mo = (mt4 << 5) + (j << 3) + (h << 2);
        f32x4 bv = *(const f32x4*)(b4 + mo);
        f32x4 res;
        #pragma unroll
        for (int q = 0; q < 4; ++q) res[q] = tacc[mt4][4 * j + q] + bv[q];
        *(f32x4*)(out + (size_t)gq * 64 + mo) = res;
      }
  }
}

// ---------------------------------------------------------------------------
extern "C" void kernel_launch(void* const* d_in, const int* in_sizes, int n_in,
                              void* d_out, int out_size, void* d_ws, size_t ws_size,
                              hipStream_t stream)
{
  const float* x     = (const float*)d_in[0];
  const float* coord = (const float*)d_in[1];
  const float* cell  = (const float*)d_in[2];
  const float* w0    = (const float*)d_in[3];
  const float* b0    = (const float*)d_in[4];
  const float* w1    = (const float*)d_in[5];
  const float* b1    = (const float*)d_in[6];
  const float* w2    = (const float*)d_in[7];
  const float* b2    = (const float*)d_in[8];
  const float* w3    = (const float*)d_in[9];
  const float* b3    = (const float*)d_in[10];
  const float* w4    = (const float*)d_in[11];
  const float* b4    = (const float*)d_in[12];
  U16* ws = (U16*)d_ws;

  hipLaunchKernelGGL(k_prep,   dim3(562), dim3(256), 0, stream, x, w0, w1, w2, w3, w4, ws);
  hipLaunchKernelGGL(k_stage1, dim3(512), dim3(256), 0, stream,
                     ws + XT_OFF, ws + W0F_OFF, b0, ws + P_OFF);
  hipLaunchKernelGGL(k_stage2, dim3(512), dim3(256), 0, stream,
                     ws + P_OFF, coord, cell, w0,
                     ws + W1F_OFF, ws + W1F_OFF + 16384, ws + W1F_OFF + 32768, ws + W4F_OFF,
                     b1, b2, b3, b4, (float*)d_out);
}

// Round 7
// 44.443 us; speedup vs baseline: 1.6241x; 1.0244x over previous
//
#include <hip/hip_runtime.h>

// ---------------------------------------------------------------------------
// LIIF forward, MI355X.
//   k_prepw  : 50 blocks — weight repack to MFMA-fragment-major f16 streams
//   k_stage1 : fused transpose+conv: reads x (NCHW f32) directly into the
//              XOR-swizzled LDS tile, then conv3x3-as-GEMM (16x16x32 MFMA)
//   k_stage2 : in-register MLP, wave = 8 queries x 4 corners = 32 cols.
//              Weights direct from global frag streams (proven r4 path).
//              32x32x16 MFMA, D->B via pack + v_permlane32_swap_b32.
// B=2, C=64, H=W=128, Q=8192 (16384 total query rows).
// NOTE: LDS weight staging (DMA or ds_write) failed 3x with unexplained
// deterministic corruption (r3/r5/r6) — do not reintroduce.
// ---------------------------------------------------------------------------

typedef unsigned short U16;
typedef unsigned int   u32;
using f16x8  = __attribute__((ext_vector_type(8)))  _Float16;
using f32x4  = __attribute__((ext_vector_type(4)))  float;
using f32x16 = __attribute__((ext_vector_type(16))) float;
using u16x8  = __attribute__((ext_vector_type(8)))  U16;
using u16x4  = __attribute__((ext_vector_type(4)))  U16;

// ws layout (f16 element offsets) — XT region retired, offsets kept stable
#define P_OFF    2097152    // 2*16384*128  = 4,194,304
#define W0F_OFF  6291456    // 73,728  stage1 A-frags: [kpos][ks][mtile][lane][8]
#define W1F_OFF  6365184    // 3*16384 stage2 A-frags: [L][s][mt][lane][8]
#define W4F_OFF  6414336    // 8,192   stage2 final:   [s][mt4][lane][8]

__device__ __forceinline__ float h2f(U16 u){ _Float16 h; __builtin_memcpy(&h,&u,2); return (float)h; }
__device__ __forceinline__ U16 f2h(float f){ _Float16 h = (_Float16)f; U16 u; __builtin_memcpy(&u,&h,2); return u; }
__device__ __forceinline__ u32 packf16(float a, float b){
  _Float16 ha = (_Float16)a, hb = (_Float16)b;
  U16 ua, ub; __builtin_memcpy(&ua,&ha,2); __builtin_memcpy(&ub,&hb,2);
  return (u32)ua | ((u32)ub << 16);
}
__device__ __forceinline__ f16x8 bfrag(const u32* w){
  union { u32 u[4]; f16x8 v; } t;
  t.u[0]=w[0]; t.u[1]=w[1]; t.u[2]=w[2]; t.u[3]=w[3];
  return t.v;
}

__device__ __forceinline__ int nearest_idx(float g){
  float t = (g + 1.0f) * 128.0f;   // exact
  t = (t - 1.0f) * 0.5f;           // exact
  float r = rintf(t);              // half-even == np.round
  r = fminf(fmaxf(r, 0.0f), 127.0f);
  return (int)r;
}
__device__ __forceinline__ float seqv(int i){ return -0.9921875f + 0.015625f*(float)i; }

// corner: 0:(-1,-1) 1:(-1,+1) 2:(+1,-1) 3:(+1,+1)
__device__ __forceinline__ void corner_calc(float c0, float c1, int corner,
                                            int& iy, int& ix, float& rel0, float& rel1){
  const float rx = 0.0078125f;
  float sx = (corner & 2) ? rx : -rx;
  float sy = (corner & 1) ? rx : -rx;
  float a0 = c0 + sx; a0 = a0 + 1e-6f; a0 = fminf(fmaxf(a0, -1.0f + 1e-6f), 1.0f - 1e-6f);
  float a1 = c1 + sy; a1 = a1 + 1e-6f; a1 = fminf(fmaxf(a1, -1.0f + 1e-6f), 1.0f - 1e-6f);
  iy = nearest_idx(a0);
  ix = nearest_idx(a1);
  rel0 = (c0 - seqv(ix)) * 128.0f;   // ref quirk: rel0 uses seq[ix]
  rel1 = (c1 - seqv(iy)) * 128.0f;
}

// ---------------------------------------------------------------------------
// k_prepw: 50 blocks.
//   [0,24)  : wL (w1/w2/w3) frag repack, block = (L, s)
//   [24,32) : w4 frag repack, block = s
//   [32,50) : w0 conv-weight frag repack, block = (kpos, ks)
__global__ __launch_bounds__(256) void k_prepw(
    const float* __restrict__ w0, const float* __restrict__ w1,
    const float* __restrict__ w2, const float* __restrict__ w3,
    const float* __restrict__ w4, U16* __restrict__ ws)
{
  __shared__ U16 sh[64 * 72];
  const int tid = threadIdx.x, bid = blockIdx.x;

  if (bid < 24) {
    // ---- wL repack: wLf[s][mt][lane][e] = wL[k*128+m],
    //      m=(mt<<5)+(lane&31), k=(s<<4)+((lane>>5)<<3)+e ----
    int L = bid >> 3, s = bid & 7;
    const float* src = (L == 0) ? w1 : (L == 1) ? w2 : w3;
    {
      int kk = tid >> 4, m0 = (tid & 15) << 3;
      const float* p = src + (((s << 4) + kk) << 7) + m0;
      float4 a = *(const float4*)p, b2v = *(const float4*)(p + 4);
      U16* d = &sh[kk * 128 + m0];
      d[0]=f2h(a.x); d[1]=f2h(a.y); d[2]=f2h(a.z); d[3]=f2h(a.w);
      d[4]=f2h(b2v.x); d[5]=f2h(b2v.y); d[6]=f2h(b2v.z); d[7]=f2h(b2v.w);
    }
    __syncthreads();
    {
      int mt = tid >> 6, lane = tid & 63;
      u16x8 o;
      #pragma unroll
      for (int e = 0; e < 8; ++e)
        o[e] = sh[((((lane >> 5) << 3) + e) << 7) + (mt << 5) + (lane & 31)];
      *(u16x8*)(ws + W1F_OFF + (L << 14) + (((s << 2) + mt) << 9) + (lane << 3)) = o;
    }
  } else if (bid < 32) {
    // ---- w4 repack: w4f[s][mt4][lane][e] = w4[k*64+m] ----
    int s = bid - 24;
    {
      int kk = tid >> 4, m0 = (tid & 15) << 2;
      float4 a = *(const float4*)(w4 + (((s << 4) + kk) << 6) + m0);
      U16* d = &sh[kk * 64 + m0];
      d[0]=f2h(a.x); d[1]=f2h(a.y); d[2]=f2h(a.z); d[3]=f2h(a.w);
    }
    __syncthreads();
    if (tid < 128) {
      int mt4 = tid >> 6, lane = tid & 63;
      u16x8 o;
      #pragma unroll
      for (int e = 0; e < 8; ++e)
        o[e] = sh[((((lane >> 5) << 3) + e) << 6) + (mt4 << 5) + (lane & 31)];
      *(u16x8*)(ws + W4F_OFF + (((s << 1) + mt4) << 9) + (lane << 3)) = o;
    }
  } else {
    // ---- w0f repack: w0f[kpos][ks][mtile][lane][e] = w0[(c*9+kpos)*128+o],
    //      o=(mtile<<4)+(lane&15), c=(ks<<5)+((lane>>4)<<3)+e ----
    int t2 = bid - 32, kpos = t2 >> 1, ks = t2 & 1;
    {
      int cc = tid >> 3, o0 = (tid & 7) << 4;
      const float* p = w0 + ((size_t)((((ks << 5) + cc) * 9) + kpos) << 7) + o0;
      #pragma unroll
      for (int j = 0; j < 4; ++j) {
        float4 v = *(const float4*)(p + (j << 2));
        U16* d = &sh[(cc << 7) + o0 + (j << 2)];
        d[0]=f2h(v.x); d[1]=f2h(v.y); d[2]=f2h(v.z); d[3]=f2h(v.w);
      }
    }
    __syncthreads();
    {
      int lane = tid & 63, mt0 = tid >> 6;
      #pragma unroll
      for (int i = 0; i < 2; ++i) {
        int mtile = mt0 + (i << 2);
        u16x8 o;
        #pragma unroll
        for (int e = 0; e < 8; ++e)
          o[e] = sh[((((lane >> 4) << 3) + e) << 7) + (mtile << 4) + (lane & 15)];
        *(u16x8*)(ws + W0F_OFF + (((((kpos << 1) + ks) << 3) + mtile) << 9) + (lane << 3)) = o;
      }
    }
  }
}

// ---------------------------------------------------------------------------
// Stage 1 (fused transpose+conv): 512 blocks: (b, y, half-row of 64 px).
// Staging: thread (c = tid&63, dy = tid>>6, dy<3 active) reads x[b][c][y+dy-1][*]
// f32 directly, converts to f16, scalar ds_write into swizzled araw:
// araw[(dy*66+xp)*64 + (c ^ ((xp&7)<<3))].  Then M=128 x N=64, K=9*64 GEMM.
__global__ __launch_bounds__(256) void k_stage1(const float* __restrict__ x,
                                                const U16* __restrict__ w0f,
                                                const float* __restrict__ b0,
                                                U16* __restrict__ P)
{
  __shared__ U16 araw[3 * 66 * 64];   // [dy][xp][c^((xp&7)<<3)], xp local 0..65
  const int tid = threadIdx.x, bid = blockIdx.x;
  const int b = bid >> 8, rem = bid & 255;
  const int y = rem >> 1, x0 = (rem & 1) << 6;

  {
    int c = tid & 63, dy = tid >> 6;
    if (dy < 3) {
      int yy = y + dy - 1;
      bool rowok = (yy >= 0) && (yy < 128);
      const float* xr = rowok
        ? (x + ((((size_t)b << 6) + c) << 14) + ((size_t)yy << 7)) : x;
      U16* arow = &araw[(dy * 66) * 64];
      // edge columns xp=0 (xs=x0-1) and xp=65 (xs=x0+64)
      {
        float v0 = 0.0f, v65 = 0.0f;
        if (rowok && x0 > 0)        v0  = xr[x0 - 1];
        if (rowok && x0 + 64 < 128) v65 = xr[x0 + 64];
        arow[0 * 64 + c] = f2h(v0);                       // xp=0: sw=0
        arow[65 * 64 + (c ^ 8)] = f2h(v65);               // xp=65: sw=8
      }
      if (rowok) {
        #pragma unroll
        for (int g = 0; g < 16; ++g) {
          float4 v = *(const float4*)(xr + x0 + (g << 2));
          #pragma unroll
          for (int j = 0; j < 4; ++j) {
            int xp = 1 + (g << 2) + j;
            float vj = (j == 0) ? v.x : (j == 1) ? v.y : (j == 2) ? v.z : v.w;
            arow[xp * 64 + (c ^ ((xp & 7) << 3))] = f2h(vj);
          }
        }
      } else {
        #pragma unroll
        for (int xp = 1; xp <= 64; ++xp)
          arow[xp * 64 + (c ^ ((xp & 7) << 3))] = f2h(0.0f);
      }
    }
  }
  __syncthreads();

  const int wv = tid >> 6, ln = tid & 63;
  const int lrow = ln & 15, lg = ln >> 4;

  f32x4 acc[2][4];
  #pragma unroll
  for (int m = 0; m < 2; ++m)
    #pragma unroll
    for (int n = 0; n < 4; ++n) acc[m][n] = (f32x4){0.f, 0.f, 0.f, 0.f};

  #pragma unroll
  for (int kpos = 0; kpos < 9; ++kpos) {
    const int dyr = kpos / 3;
    const int dx = kpos % 3 - 1;
    f16x8 a[2][2];
    #pragma unroll
    for (int mf = 0; mf < 2; ++mf)
      #pragma unroll
      for (int ks = 0; ks < 2; ++ks) {
        size_t off = ((size_t)((((kpos << 1) + ks) << 3) + ((wv << 1) + mf)) << 9) + (ln << 3);
        a[mf][ks] = *(const f16x8*)(w0f + off);
      }
    #pragma unroll
    for (int ks = 0; ks < 2; ++ks)
      #pragma unroll
      for (int nf = 0; nf < 4; ++nf) {
        int xp = (nf << 4) + lrow + dx + 1;
        int cc = ((ks << 5) + (lg << 3)) ^ ((xp & 7) << 3);
        f16x8 bf = *(const f16x8*)(&araw[(dyr * 66 + xp) * 64 + cc]);
        acc[0][nf] = __builtin_amdgcn_mfma_f32_16x16x32_f16(a[0][ks], bf, acc[0][nf], 0, 0, 0);
        acc[1][nf] = __builtin_amdgcn_mfma_f32_16x16x32_f16(a[1][ks], bf, acc[1][nf], 0, 0, 0);
      }
  }

  #pragma unroll
  for (int mf = 0; mf < 2; ++mf) {
    int o0 = (wv << 5) + (mf << 4) + (lg << 2);
    float bb[4];
    #pragma unroll
    for (int r = 0; r < 4; ++r) bb[r] = b0[o0 + r];
    #pragma unroll
    for (int nf = 0; nf < 4; ++nf) {
      int px = x0 + (nf << 4) + lrow;
      u16x4 w;
      #pragma unroll
      for (int r = 0; r < 4; ++r) w[r] = f2h(acc[mf][nf][r] + bb[r]);
      *(u16x4*)(P + ((size_t)((b << 14) + (y << 7) + px)) * 128 + o0) = w;
    }
  }
}

// ---------------------------------------------------------------------------
// Stage 2: wave = 8 queries x 4 corners. col=lane&31: qi=col>>2, c=col&3.
// Weights read directly from global frag streams (proven r4 path).
// B-frag (32x32x16): n=col, k=16s+8h+e.  D: n=col, m=(r&3)+8(r>>2)+4h.
// D->nextB: p[j]=pack(d2j,d2j+1); permlane32_swap(p[w+4u],p[w+4u+2]).
__global__ __launch_bounds__(256) void k_stage2(
    const U16* __restrict__ P,
    const float* __restrict__ coord, const float* __restrict__ cell,
    const float* __restrict__ w0,
    const U16* __restrict__ w1f, const U16* __restrict__ w2f,
    const U16* __restrict__ w3f, const U16* __restrict__ w4f,
    const float* __restrict__ b1, const float* __restrict__ b2,
    const float* __restrict__ b3, const float* __restrict__ b4,
    float* __restrict__ out)
{
  const int tid = threadIdx.x;
  const int wv = tid >> 6, ln = tid & 63;
  const int wave = blockIdx.x * 4 + wv;
  const int q0 = wave << 3;
  const int col = ln & 31, h = ln >> 5;
  const int qi = col >> 2, c = col & 3;
  const int gq = q0 + qi;
  const int bimg = gq >> 13;

  // ---- per-query corner math ----
  float c0v = coord[gq * 2 + 0], c1v = coord[gq * 2 + 1];
  float rc0 = cell[gq * 2 + 0] * 128.0f, rc1 = cell[gq * 2 + 1] * 128.0f;
  int lin4[4]; float r0v[4], r1v[4], area[4];
  #pragma unroll
  for (int c4 = 0; c4 < 4; ++c4) {
    int iy, ix; float r0, r1;
    corner_calc(c0v, c1v, c4, iy, ix, r0, r1);
    lin4[c4] = iy * 128 + ix;
    r0v[c4] = r0; r1v[c4] = r1;
    area[c4] = fabsf(r0 * r1) + 1e-9f;
  }
  float tot = ((area[0] + area[1]) + area[2]) + area[3];
  float wgt = area[3 - c] / tot;           // perm = (3,2,1,0)
  float rel0 = r0v[c], rel1 = r1v[c];

  // ---- P row prefetch (8 independent 16B loads) ----
  const U16* Pr = P + ((size_t)(bimg << 14) + lin4[c]) * 128;
  u16x8 pv[8];
  #pragma unroll
  for (int s = 0; s < 8; ++s)
    pv[s] = *(const u16x8*)(Pr + (s << 4) + (h << 3));

  // ---- h0 -> Bf ----
  u32 Bf[8][4];
  {
    const float* tu = w0 + 576 * 128;
    const float* tv = tu + 128;
    const float* ts2 = tv + 128;
    const float* tt = ts2 + 128;
    #pragma unroll
    for (int s = 0; s < 8; ++s) {
      int k0 = (s << 4) + (h << 3);
      f32x4 ua = *(const f32x4*)(tu + k0),  ub = *(const f32x4*)(tu + k0 + 4);
      f32x4 va = *(const f32x4*)(tv + k0),  vb = *(const f32x4*)(tv + k0 + 4);
      f32x4 sa = *(const f32x4*)(ts2 + k0), sb = *(const f32x4*)(ts2 + k0 + 4);
      f32x4 ta = *(const f32x4*)(tt + k0),  tb = *(const f32x4*)(tt + k0 + 4);
      float hh[8];
      #pragma unroll
      for (int e = 0; e < 8; ++e) {
        float uu = (e < 4) ? ua[e & 3] : ub[e & 3];
        float vvv = (e < 4) ? va[e & 3] : vb[e & 3];
        float ss = (e < 4) ? sa[e & 3] : sb[e & 3];
        float t2 = (e < 4) ? ta[e & 3] : tb[e & 3];
        hh[e] = fmaxf(h2f(pv[s][e]) + rel0 * uu + rel1 * vvv + rc0 * ss + rc1 * t2, 0.0f);
      }
      #pragma unroll
      for (int w = 0; w < 4; ++w)
        Bf[s][w] = packf16(hh[2 * w], hh[2 * w + 1]);
    }
  }

  // ---- hidden layers 1..3 (weights direct from global) ----
  const U16* wf_[3] = {w1f, w2f, w3f};
  const float* bL_[3] = {b1, b2, b3};
  #pragma unroll
  for (int L = 0; L < 3; ++L) {
    const U16* wf = wf_[L];
    const float* bL = bL_[L];
    f32x16 acc[4];
    #pragma unroll
    for (int mt = 0; mt < 4; ++mt)
      #pragma unroll
      for (int j = 0; j < 4; ++j) {
        f32x4 bv = *(const f32x4*)(bL + (mt << 5) + (j << 3) + (h << 2));
        #pragma unroll
        for (int q = 0; q < 4; ++q) acc[mt][4 * j + q] = bv[q];
      }
    #pragma unroll
    for (int s = 0; s < 8; ++s) {
      f16x8 B = bfrag(Bf[s]);
      #pragma unroll
      for (int mt = 0; mt < 4; ++mt) {
        f16x8 A = *(const f16x8*)(wf + (((size_t)(s * 4 + mt) * 64 + ln) << 3));
        acc[mt] = __builtin_amdgcn_mfma_f32_32x32x16_f16(A, B, acc[mt], 0, 0, 0);
      }
    }
    // D -> next-layer B
    #pragma unroll
    for (int mtp = 0; mtp < 4; ++mtp) {
      u32 p[8];
      #pragma unroll
      for (int j2 = 0; j2 < 8; ++j2)
        p[j2] = packf16(fmaxf(acc[mtp][2 * j2], 0.0f), fmaxf(acc[mtp][2 * j2 + 1], 0.0f));
      #pragma unroll
      for (int u = 0; u < 2; ++u)
        #pragma unroll
        for (int w = 0; w < 2; ++w) {
          u32 va = p[w + 4 * u], vb = p[w + 4 * u + 2];
          asm("v_permlane32_swap_b32 %0, %1" : "+v"(va), "+v"(vb));
          Bf[2 * mtp + u][w]     = va;
          Bf[2 * mtp + u][w + 2] = vb;
        }
    }
  }

  // ---- final layer 128 -> 64 ----
  f32x16 a4[2];
  #pragma unroll
  for (int mt4 = 0; mt4 < 2; ++mt4)
    #pragma unroll
    for (int r = 0; r < 16; ++r) a4[mt4][r] = 0.0f;
  #pragma unroll
  for (int s = 0; s < 8; ++s) {
    f16x8 B = bfrag(Bf[s]);
    #pragma unroll
    for (int mt4 = 0; mt4 < 2; ++mt4) {
      f16x8 A = *(const f16x8*)(w4f + (((size_t)(s * 2 + mt4) * 64 + ln) << 3));
      a4[mt4] = __builtin_amdgcn_mfma_f32_32x32x16_f16(A, B, a4[mt4], 0, 0, 0);
    }
  }

  // ---- area-weighted corner combine across 4-lane groups ----
  float tacc[2][16];
  #pragma unroll
  for (int mt4 = 0; mt4 < 2; ++mt4)
    #pragma unroll
    for (int r = 0; r < 16; ++r) {
      float v = a4[mt4][r] * wgt;
      v += __shfl_xor(v, 1, 64);
      v += __shfl_xor(v, 2, 64);
      tacc[mt4][r] = v;
    }

  if (c == 0) {
    #pragma unroll
    for (int mt4 = 0; mt4 < 2; ++mt4)
      #pragma unroll
      for (int j = 0; j < 4; ++j) {
        int mo = (mt4 << 5) + (j << 3) + (h << 2);
        f32x4 bv = *(const f32x4*)(b4 + mo);
        f32x4 res;
        #pragma unroll
        for (int q = 0; q < 4; ++q) res[q] = tacc[mt4][4 * j + q] + bv[q];
        *(f32x4*)(out + (size_t)gq * 64 + mo) = res;
      }
  }
}

// ---------------------------------------------------------------------------
extern "C" void kernel_launch(void* const* d_in, const int* in_sizes, int n_in,
                              void* d_out, int out_size, void* d_ws, size_t ws_size,
                              hipStream_t stream)
{
  const float* x     = (const float*)d_in[0];
  const float* coord = (const float*)d_in[1];
  const float* cell  = (const float*)d_in[2];
  const float* w0    = (const float*)d_in[3];
  const float* b0    = (const float*)d_in[4];
  const float* w1    = (const float*)d_in[5];
  const float* b1    = (const float*)d_in[6];
  const float* w2    = (const float*)d_in[7];
  const float* b2    = (const float*)d_in[8];
  const float* w3    = (const float*)d_in[9];
  const float* b3    = (const float*)d_in[10];
  const float* w4    = (const float*)d_in[11];
  const float* b4    = (const float*)d_in[12];
  U16* ws = (U16*)d_ws;

  hipLaunchKernelGGL(k_prepw,  dim3(50),  dim3(256), 0, stream, w0, w1, w2, w3, w4, ws);
  hipLaunchKernelGGL(k_stage1, dim3(512), dim3(256), 0, stream,
                     x, ws + W0F_OFF, b0, ws + P_OFF);
  hipLaunchKernelGGL(k_stage2, dim3(512), dim3(256), 0, stream,
                     ws + P_OFF, coord, cell, w0,
                     ws + W1F_OFF, ws + W1F_OFF + 16384, ws + W1F_OFF + 32768, ws + W4F_OFF,
                     b1, b2, b3, b4, (float*)d_out);
}